// Round 3
// baseline (791.135 us; speedup 1.0000x reference)
//
#include <hip/hip_runtime.h>
#include <hip/hip_bf16.h>
#include <cstdint>
#include <cstddef>

// Problem dims (fixed)
#define NB   4096      // batch rows
#define DIN  1024
#define DM   2048
#define DFF  8192

typedef int   i32x4 __attribute__((ext_vector_type(4)));
typedef float f32x4 __attribute__((ext_vector_type(4)));

__device__ __forceinline__ unsigned short f2bf(float f) {
  union { __hip_bfloat16 h; unsigned short u; } v;
  v.h = __float2bfloat16(f);
  return v.u;
}

__device__ __forceinline__ f32x4 mfma_bf16_16x16x32(i32x4 a, i32x4 b, f32x4 c) {
  asm("v_mfma_f32_16x16x32_bf16 %0, %1, %2, %0" : "+v"(c) : "v"(a), "v"(b));
  return c;
}

// Stage a 128x32 bf16 tile (rows x k) from global (row-major, leading dim ld)
// into linear LDS [128][32] via global_load_lds (16B per lane).
__device__ __forceinline__ void stage128x32(const unsigned short* __restrict__ g, int ld,
                                            unsigned short* s, int wave, int lane) {
#pragma unroll
  for (int i = 0; i < 2; ++i) {
    const int r = i * 64 + wave * 16 + (lane >> 2);
    const int c = (lane & 3) * 8;
    const unsigned short* gp = g + (size_t)r * ld + c;
    unsigned short* lp = s + (i * 64 + wave * 16) * 32;  // wave-uniform base; HW adds lane*16B
    __builtin_amdgcn_global_load_lds(
        (const __attribute__((address_space(1))) unsigned int*)gp,
        (__attribute__((address_space(3))) unsigned int*)lp,
        16, 0, 0);
  }
}

// C = A @ B^T + bias, A: MxK bf16 row-major, B: NxK bf16 row-major.
// EP: 0 = fp32 out; 1 = bf16 out; 2 = gelu(exact) -> bf16; 3 = sigmoid-gate -> fp32;
//     4 = residual (+aux0) dual fp32 write (Cf and C2).
template<int EP>
__global__ __launch_bounds__(256)
void gemm_bt(const unsigned short* __restrict__ A, const unsigned short* __restrict__ Bw,
             const float* __restrict__ bias,
             float* __restrict__ Cf, unsigned short* __restrict__ Ch,
             int M, int N, int K,
             const float* __restrict__ aux0,   // h_prev (EP3) / h_hat (EP4)
             const float* __restrict__ ga, const float* __restrict__ gb,
             float* __restrict__ C2) {
  constexpr int BM = 128, BN = 128, BK = 32;
  __shared__ __align__(16) unsigned short sA[2][BM * BK];
  __shared__ __align__(16) unsigned short sB[2][BN * BK];
  const int tid = threadIdx.x;
  const int wave = tid >> 6, lane = tid & 63;
  const int wr = wave >> 1, wc = wave & 1;
  const int row0 = blockIdx.y * BM, col0 = blockIdx.x * BN;

  const unsigned short* Ag = A + (size_t)row0 * K;
  const unsigned short* Bg = Bw + (size_t)col0 * K;

  f32x4 acc[4][4] = {};

  stage128x32(Ag, K, &sA[0][0], wave, lane);
  stage128x32(Bg, K, &sB[0][0], wave, lane);
  __syncthreads();  // compiler emits vmcnt(0) drain before barrier

  const int KT = K / BK;
  for (int kt = 0; kt < KT; ++kt) {
    const int cur = kt & 1;
    if (kt + 1 < KT) {
      stage128x32(Ag + (size_t)(kt + 1) * BK, K, &sA[cur ^ 1][0], wave, lane);
      stage128x32(Bg + (size_t)(kt + 1) * BK, K, &sB[cur ^ 1][0], wave, lane);
    }
    const unsigned short* pa = &sA[cur][0];
    const unsigned short* pb = &sB[cur][0];
    const int kb = (lane >> 4) * 8;
    i32x4 af[4], bv[4];
#pragma unroll
    for (int m = 0; m < 4; ++m)
      af[m] = *(const i32x4*)(pa + (wr * 64 + m * 16 + (lane & 15)) * BK + kb);
#pragma unroll
    for (int n = 0; n < 4; ++n)
      bv[n] = *(const i32x4*)(pb + (wc * 64 + n * 16 + (lane & 15)) * BK + kb);
#pragma unroll
    for (int m = 0; m < 4; ++m)
#pragma unroll
      for (int n = 0; n < 4; ++n)
        acc[m][n] = mfma_bf16_16x16x32(af[m], bv[n], acc[m][n]);
    __syncthreads();
  }

  // Epilogue. C/D frag: col = lane&15, row = (lane>>4)*4 + reg.
  const int lr = (lane >> 4) * 4;
  const int lc = lane & 15;
#pragma unroll
  for (int m = 0; m < 4; ++m) {
    const int rbase = row0 + wr * 64 + m * 16 + lr;
#pragma unroll
    for (int n = 0; n < 4; ++n) {
      const int col = col0 + wc * 64 + n * 16 + lc;
      const float bvl = bias[col];
      float s1 = 0.f, s2 = 0.f;
      if (EP == 3) {
        s1 = 1.f / (1.f + expf(-ga[col]));
        s2 = 1.f / (1.f + expf(-gb[col]));
      }
#pragma unroll
      for (int r = 0; r < 4; ++r) {
        const int row = rbase + r;
        const size_t idx = (size_t)row * N + col;
        float v = acc[m][n][r] + bvl;
        if (EP == 0) {
          Cf[idx] = v;
        } else if (EP == 1) {
          Ch[idx] = f2bf(v);
        } else if (EP == 2) {
          Ch[idx] = f2bf(0.5f * v * (1.f + erff(v * 0.70710678118654752f)));
        } else if (EP == 3) {
          Cf[idx] = s1 * aux0[idx] + s2 * v;
        } else {
          const float o = aux0[idx] + v;
          Cf[idx] = o;
          C2[idx] = o;
        }
      }
    }
  }
}

__global__ __launch_bounds__(256)
void conv_f32_bf16(const float* __restrict__ in, unsigned short* __restrict__ out, long n4) {
  long i = (long)blockIdx.x * blockDim.x + threadIdx.x;
  const long stride = (long)gridDim.x * blockDim.x;
  for (; i < n4; i += stride) {
    const float4 v = ((const float4*)in)[i];
    short4 o;
    o.x = (short)f2bf(v.x);
    o.y = (short)f2bf(v.y);
    o.z = (short)f2bf(v.z);
    o.w = (short)f2bf(v.w);
    ((short4*)out)[i] = o;
  }
}

// One block (256 threads) per row; D=2048 fp32 in -> bf16 out.
__global__ __launch_bounds__(256)
void ln_rows(const float* __restrict__ x, const float* __restrict__ g,
             const float* __restrict__ b, unsigned short* __restrict__ out) {
  constexpr int D = 2048;
  const int row = blockIdx.x;
  const int t = threadIdx.x;
  const float4* xr = (const float4*)(x + (size_t)row * D);
  const float4 v0 = xr[t], v1 = xr[t + 256];
  float s = v0.x + v0.y + v0.z + v0.w + v1.x + v1.y + v1.z + v1.w;
  float q = v0.x * v0.x + v0.y * v0.y + v0.z * v0.z + v0.w * v0.w +
            v1.x * v1.x + v1.y * v1.y + v1.z * v1.z + v1.w * v1.w;
#pragma unroll
  for (int off = 32; off > 0; off >>= 1) {
    s += __shfl_xor(s, off);
    q += __shfl_xor(q, off);
  }
  __shared__ float ss[4], sq[4];
  if ((t & 63) == 0) { ss[t >> 6] = s; sq[t >> 6] = q; }
  __syncthreads();
  s = ss[0] + ss[1] + ss[2] + ss[3];
  q = sq[0] + sq[1] + sq[2] + sq[3];
  const float mean = s * (1.f / D);
  const float inv = rsqrtf(q * (1.f / D) - mean * mean + 1e-5f);
  const float4* gp = (const float4*)g;
  const float4* bp = (const float4*)b;
  short4* op = (short4*)(out + (size_t)row * D);
#pragma unroll
  for (int h = 0; h < 2; ++h) {
    const int ti = t + h * 256;
    const float4 v = h ? v1 : v0;
    const float4 gg = gp[ti], bb = bp[ti];
    short4 o;
    o.x = (short)f2bf((v.x - mean) * inv * gg.x + bb.x);
    o.y = (short)f2bf((v.y - mean) * inv * gg.y + bb.y);
    o.z = (short)f2bf((v.z - mean) * inv * gg.z + bb.z);
    o.w = (short)f2bf((v.w - mean) * inv * gg.w + bb.w);
    op[ti] = o;
  }
}

extern "C" void kernel_launch(void* const* d_in, const int* in_sizes, int n_in,
                              void* d_out, int out_size, void* d_ws, size_t ws_size,
                              hipStream_t stream) {
  const float* x_t    = (const float*)d_in[0];
  const float* h_prev = (const float*)d_in[1];
  const float* W_proj = (const float*)d_in[2];
  const float* b_proj = (const float*)d_in[3];
  const float* in_w   = (const float*)d_in[4];
  const float* in_b   = (const float*)d_in[5];
  const float* out_w  = (const float*)d_in[6];
  const float* out_b  = (const float*)d_in[7];
  const float* ln1_g  = (const float*)d_in[8];
  const float* ln1_b  = (const float*)d_in[9];
  const float* ln2_g  = (const float*)d_in[10];
  const float* ln2_b  = (const float*)d_in[11];
  const float* gate_a = (const float*)d_in[12];
  const float* gate_b = (const float*)d_in[13];
  const float* ffn_w1 = (const float*)d_in[14];
  const float* ffn_b1 = (const float*)d_in[15];
  const float* ffn_w2 = (const float*)d_in[16];
  const float* ffn_b2 = (const float*)d_in[17];
  float* out = (float*)d_out;

  char* ws = (char*)d_ws;
  const size_t MB = 1024 * 1024;
  // Region plan (208 MB total, with lifetime-based reuse):
  unsigned short* gelubf = (unsigned short*)(ws);             // 64MB (lives: GEMM4->5)
  unsigned short* xtbf   = (unsigned short*)(ws);             // 8MB  (lives: conv->GEMM1)
  unsigned short* wpbf   = (unsigned short*)(ws + 8 * MB);    // 4MB  (lives: conv->GEMM1)
  float*          xh     = (float*)(ws + 64 * MB);            // 32MB (x, then h_hat)
  unsigned short* qybf   = (unsigned short*)(ws + 96 * MB);   // 16MB (qn, then y)
  unsigned short* vbf    = (unsigned short*)(ws + 112 * MB);  // 16MB
  unsigned short* wvbf   = (unsigned short*)(ws + 128 * MB);  // 8MB
  unsigned short* owbf   = (unsigned short*)(ws + 136 * MB);  // 8MB
  unsigned short* w1bf   = (unsigned short*)(ws + 144 * MB);  // 32MB
  unsigned short* w2bf   = (unsigned short*)(ws + 176 * MB);  // 32MB

  // fp32 -> bf16 converts (only the v-slice of in_proj_w is ever needed:
  // softmax over the singleton key axis is exactly 1, so ctx == v).
  conv_f32_bf16<<<2048, 256, 0, stream>>>(x_t, xtbf, (long)NB * DIN / 4);
  conv_f32_bf16<<<2048, 256, 0, stream>>>(W_proj, wpbf, (long)DM * DIN / 4);
  conv_f32_bf16<<<2048, 256, 0, stream>>>(in_w + 2L * DM * DM, wvbf, (long)DM * DM / 4);
  conv_f32_bf16<<<2048, 256, 0, stream>>>(out_w, owbf, (long)DM * DM / 4);
  conv_f32_bf16<<<4096, 256, 0, stream>>>(ffn_w1, w1bf, (long)DFF * DM / 4);
  conv_f32_bf16<<<4096, 256, 0, stream>>>(ffn_w2, w2bf, (long)DM * DFF / 4);

  const dim3 blk(256);
  const dim3 gD(DM / 128, NB / 128);    // (16, 32)
  const dim3 gF(DFF / 128, NB / 128);   // (64, 32)

  // x = x_t @ W_proj^T + b_proj           (fp32 out)
  gemm_bt<0><<<gD, blk, 0, stream>>>(xtbf, wpbf, b_proj, xh, nullptr,
                                     NB, DM, DIN, nullptr, nullptr, nullptr, nullptr);
  // qn = LN1(x)                           (bf16 out)
  ln_rows<<<NB, blk, 0, stream>>>(xh, ln1_g, ln1_b, qybf);
  // v = qn @ Wv^T + bv                    (bf16 out)
  gemm_bt<1><<<gD, blk, 0, stream>>>(qybf, wvbf, in_b + 2 * DM, nullptr, vbf,
                                     NB, DM, DM, nullptr, nullptr, nullptr, nullptr);
  // h_hat = sig(ga)*h_prev + sig(gb)*(v @ out_w^T + out_b)   (fp32 out, into xh)
  gemm_bt<3><<<gD, blk, 0, stream>>>(vbf, owbf, out_b, xh, nullptr,
                                     NB, DM, DM, h_prev, gate_a, gate_b, nullptr);
  // y = LN2(h_hat)                        (bf16 out)
  ln_rows<<<NB, blk, 0, stream>>>(xh, ln2_g, ln2_b, qybf);
  // g1 = gelu(y @ ffn_w1^T + b1)          (bf16 out)
  gemm_bt<2><<<gF, blk, 0, stream>>>(qybf, w1bf, ffn_b1, nullptr, gelubf,
                                     NB, DFF, DM, nullptr, nullptr, nullptr, nullptr);
  // h_new = h_hat + g1 @ ffn_w2^T + b2    (fp32, dual write to both output halves)
  gemm_bt<4><<<gD, blk, 0, stream>>>(gelubf, w2bf, ffn_b2, out, nullptr,
                                     NB, DM, DFF, xh, nullptr, nullptr,
                                     out + (size_t)NB * DM);
}